// Round 11
// baseline (96.733 us; speedup 1.0000x reference)
//
#include <hip/hip_runtime.h>
#include <hip/hip_bf16.h>

typedef short bf16x8 __attribute__((ext_vector_type(8)));
typedef float f32x4 __attribute__((ext_vector_type(4)));
typedef unsigned int u32;
typedef u32 u32x4 __attribute__((ext_vector_type(4)));

#define T_SEQ 2048
#define NB 8
#define NEGB (-1e30f)

__device__ inline unsigned short f2bf(float f) {
  unsigned u = __builtin_bit_cast(unsigned, f);
  u += 0x7FFFu + ((u >> 16) & 1u);   // round-to-nearest-even
  return (unsigned short)(u >> 16);
}
__device__ inline float bf2f(unsigned short h) {
  unsigned u = ((unsigned)h) << 16;
  return __builtin_bit_cast(float, u);
}
__device__ inline u32 cvt2(float a, float b) {  // v_cvt_pk_bf16_f32 via HIP
  __hip_bfloat162 h = __float22bfloat162_rn(make_float2(a, b));
  u32 r;
  __builtin_memcpy(&r, &h, 4);
  return r;
}
__device__ inline bf16x8 pack8(float4 a, float4 b) {
  u32x4 p;
  p[0] = cvt2(a.x, a.y);
  p[1] = cvt2(a.z, a.w);
  p[2] = cvt2(b.x, b.y);
  p[3] = cvt2(b.z, b.w);
  return __builtin_bit_cast(bf16x8, p);
}
__device__ inline f32x4 mfma16(bf16x8 a, bf16x8 b, f32x4 c) {
  return __builtin_amdgcn_mfma_f32_16x16x32_bf16(a, b, c, 0, 0, 0);
}
// async 16B global -> LDS (DMA). ldsptr wave-uniform; lane l lands at +l*16.
__device__ __forceinline__ void gl_lds16(const void* g, void* l) {
  __builtin_amdgcn_global_load_lds(
      (const __attribute__((address_space(1))) void*)g,
      (__attribute__((address_space(3))) void*)l, 16, 0, 0);
}
// non-temporal variant: aux=2 -> 'nt' cpol (stream past L2/L3, no allocate).
// X is 192MB read-once-per-launch; NT avoids the L3 eviction-scatter regime
// (warm replays showed 52% cache-line-grained HBM misses at 1.27 TB/s).
__device__ __forceinline__ void gl_lds16_nt(const void* g, void* l) {
  __builtin_amdgcn_global_load_lds(
      (const __attribute__((address_space(1))) void*)g,
      (__attribute__((address_space(3))) void*)l, 16, 0, 2);
}

// ---- meta: pad_mask dtype detect (redundant per block) + lengths ----------
__global__ void meta_k(const unsigned char* m, int* lengths) {
  int b = blockIdx.x, tid = threadIdx.x;
  int lo = 0, lb = 0;
  for (int i = tid; i < NB * T_SEQ; i += 256) {
    int v = (m[i] != 0);
    lo += v;
    if (i & 3) lb += v;
  }
  for (int off = 32; off >= 1; off >>= 1) {
    lo += __shfl_xor(lo, off);
    lb += __shfl_xor(lb, off);
  }
  __shared__ int s0[4], s1[4], ws2[4];
  if ((tid & 63) == 0) { s0[tid >> 6] = lo; s1[tid >> 6] = lb; }
  __syncthreads();
  int ones = s0[0] + s0[1] + s0[2] + s0[3];
  int bad = s1[0] + s1[1] + s1[2] + s1[3];
  int flag = (ones > 0 && bad == 0);  // 1 => int32 storage
  int cnt = 0;
  if (flag) {
    const int* mi = (const int*)m;
    for (int t = tid; t < T_SEQ; t += 256) cnt += (mi[b * T_SEQ + t] == 0);
  } else {
    for (int t = tid; t < T_SEQ; t += 256) cnt += (m[b * T_SEQ + t] == 0);
  }
  for (int off = 32; off >= 1; off >>= 1) cnt += __shfl_xor(cnt, off);
  __syncthreads();
  if ((tid & 63) == 0) ws2[tid >> 6] = cnt;
  __syncthreads();
  if (tid == 0) lengths[b] = ws2[0] + ws2[1] + ws2[2] + ws2[3];
}

// WT[mi][n][k] (bf16) = W_mi[k][n]
__global__ void wt_k(const float* Wq, const float* Wk, const float* Wv,
                     unsigned short* wt) {
  int e = blockIdx.x * 256 + threadIdx.x;
  if (e >= 3 * 64 * 1024) return;
  int mi = e >> 16;
  int rem = e & 65535;
  int kk = rem & 1023, n = rem >> 10;
  const float* W = (mi == 0) ? Wq : (mi == 1) ? Wk : Wv;
  wt[e] = f2bf(W[kk * 64 + n]);
}

// Projection GEMM (R6 structure; single change this round: NT loads for X).
__global__ __launch_bounds__(512, 4) void proj_k(
    const float* Q, const float* K, const float* V, const unsigned short* wt,
    unsigned short* qo, unsigned short* ko, unsigned short* vTb, float* vmsum) {
  __shared__ float xs[2][4096];          // 16 KB x2: [row][k] f32 (pre-swizzled)
  __shared__ unsigned short wss[2][4096];// 8 KB x2: [n][k] bf16 (pre-swizzled)
  int mi = blockIdx.y;
  const float* X = (mi == 0) ? Q : (mi == 1) ? K : V;
  const unsigned short* wtm = wt + mi * 65536;
  int tid = threadIdx.x;
  int w = tid >> 6, lane = tid & 63, l15 = lane & 15, g = lane >> 4;
  int wr = w >> 1, wc = w & 1;
  int r0b = blockIdx.x * 64;

  // staging addresses: per wave exactly 3 gl_lds instrs/chunk
  int segA = w * 2;
  int rowA0 = segA * 4 + (lane >> 4);
  int rowA1 = rowA0 + 4;
  int colA0 = ((lane & 15) ^ (rowA0 & 15)) * 4;
  int colA1 = ((lane & 15) ^ (rowA1 & 15)) * 4;
  const float* srcA0 = X + (size_t)(r0b + rowA0) * 1024 + colA0;
  const float* srcA1 = X + (size_t)(r0b + rowA1) * 1024 + colA1;
  int nW = w * 8 + (lane >> 3);
  int skW = ((lane & 7) ^ (nW & 7)) * 8;
  const unsigned short* srcW = wtm + (size_t)nW * 1024 + skW;

  f32x4 acc[2];
  acc[0] = 0; acc[1] = 0;

#define STAGE(buf, kc2)                                          \
  do {                                                           \
    gl_lds16_nt(srcA0 + (kc2) * 64, &xs[buf][segA * 256]);       \
    gl_lds16_nt(srcA1 + (kc2) * 64, &xs[buf][segA * 256 + 256]); \
    gl_lds16(srcW + (kc2) * 64, &wss[buf][w * 512]);             \
  } while (0)

  STAGE(0, 0);  // prologue: chunk 0 in flight

  int arow = wr * 16 + l15;
  for (int kc = 0; kc < 16; ++kc) {
    int cur = kc & 1;
    if (kc < 15) {
      STAGE(cur ^ 1, kc + 1);  // overwrite-safe: post-compute barrier of kc-1
      // wait chunk kc only; chunk kc+1's 3 loads REMAIN IN FLIGHT (T4)
      asm volatile("s_waitcnt vmcnt(3)" ::: "memory");
    } else {
      asm volatile("s_waitcnt vmcnt(0)" ::: "memory");
    }
    __builtin_amdgcn_s_barrier();  // raw: no compiler vmcnt(0) drain
#pragma unroll
    for (int ks = 0; ks < 2; ++ks) {
      int lb0 = ks * 8 + g * 2;
      float4 fa = *(const float4*)&xs[cur][arow * 64 + ((lb0 ^ l15) * 4)];
      float4 fb = *(const float4*)&xs[cur][arow * 64 + (((lb0 + 1) ^ l15) * 4)];
      bf16x8 a = pack8(fa, fb);
#pragma unroll
      for (int nt = 0; nt < 2; ++nt) {
        int nrow = wc * 32 + nt * 16 + l15;
        bf16x8 bb = *(const bf16x8*)
            &wss[cur][nrow * 64 + (((ks * 4 + g) ^ (l15 & 7)) * 8)];
        acc[nt] = mfma16(a, bb, acc[nt]);
      }
    }
    if (kc < 15) {
      // my LDS reads must retire before others' next STAGE overwrites
      asm volatile("s_waitcnt lgkmcnt(0)" ::: "memory");
      __builtin_amdgcn_s_barrier();
    }
  }
#undef STAGE

  // D layout: col = lane&15, row = g*4 + vv
#pragma unroll
  for (int nt = 0; nt < 2; ++nt)
#pragma unroll
    for (int vv = 0; vv < 4; ++vv) {
      int rr = r0b + wr * 16 + g * 4 + vv;
      int c = wc * 32 + nt * 16 + l15;
      float val = acc[nt][vv];
      if (mi == 0) {
        qo[(size_t)rr * 64 + c] = f2bf(val * 0.03125f);  // fold C^-0.5
      } else if (mi == 1) {
        ko[(size_t)rr * 64 + c] = f2bf(val);
      } else {
        int bb = rr >> 11, ts = rr & 2047;
        // tile-blocked vT: [b][t/32][d][t%32]
        vTb[(((size_t)bb * 64 + (ts >> 5)) * 64 + c) * 32 + (ts & 31)] =
            f2bf(val);
      }
    }

  if (mi == 2) {  // fold v column-sums into vmsum[b][d] (replaces vmean_k)
    float ps0 = acc[0][0] + acc[0][1] + acc[0][2] + acc[0][3];
    float ps1 = acc[1][0] + acc[1][1] + acc[1][2] + acc[1][3];
    __syncthreads();  // K-loop LDS fully retired; reuse xs as scratch
    float* rb = (float*)xs;  // [64 cols][16 contributors]
    rb[(wc * 32 + l15) * 16 + (wr * 4 + g)] = ps0;
    rb[(wc * 32 + 16 + l15) * 16 + (wr * 4 + g)] = ps1;
    __syncthreads();
    if (tid < 64) {
      float s = 0.f;
#pragma unroll
      for (int i = 0; i < 16; ++i) s += rb[tid * 16 + i];
      atomicAdd(&vmsum[(blockIdx.x >> 5) * 64 + tid], s);
    }
  }
}

// Flash attention: 512 threads = 8 waves = 4 key-chunks x 2 row-groups;
// 32 q-rows per block; 512 blocks (2/CU), complementary work pairing.
// T14: K/V frags for tile tt+1 issued right after tt's QK MFMAs.
__global__ __launch_bounds__(512, 4) void attn_k(
    const unsigned short* q, const unsigned short* k, const unsigned short* vTb,
    const float* vmsum, const int* lengths, float* Out) {
  __shared__ unsigned short pL[8][16][40];      // per-wave P round-trip
  __shared__ unsigned short oP[4][2][16][64];   // bf16 partial O [j][r][row][col]
  __shared__ float mP[4][2][16], lP[4][2][16];

  // complementary work pairing: co-resident blocks sum to ~constant work
  int id = blockIdx.x;
  int raw = id & 63, b = id >> 6;
  int xx = (raw + 8 * b) & 63;
  int tile = (xx < 32) ? xx : 95 - xx;   // bijective on 0..63
  int t0 = tile * 32;

  int tid = threadIdx.x;
  int w = tid >> 6, lane = tid & 63;
  int j = w >> 1, r = w & 1;
  int l15 = lane & 15, g = lane >> 4;
  int t_base = t0 + r * 16;

  const bf16x8* qrow =
      (const bf16x8*)(q + ((size_t)b * T_SEQ + t_base + l15) * 64);
  bf16x8 aq0 = qrow[g];
  bf16x8 aq1 = qrow[4 + g];

  f32x4 o[4];
  float m[4], l[4];
#pragma unroll
  for (int i = 0; i < 4; ++i) { o[i] = 0; m[i] = NEGB; l[i] = 0.f; }

  const bf16x8* kch = (const bf16x8*)k + (size_t)b * T_SEQ * 8;
  const unsigned short* vch = vTb + (size_t)b * 131072;

  // balanced contiguous tile-chunks over this block's NT key-tiles
  int NT = tile + 1;
  int qn = NT >> 2, rem = NT & 3;
  int start = j * qn + (j < rem ? j : rem);
  int end = start + qn + (j < rem ? 1 : 0);
  int capw = ((t_base + 15) >> 5) + 1;
  if (end > capw) end = capw;

  bf16x8 kb00, kb01, kb10, kb11, bv0, bv1, bv2, bv3;
  if (start < end) {  // prologue loads for first tile
    int s0 = start * 32;
    kb00 = kch[(size_t)(s0 + l15) * 8 + g];
    kb01 = kch[(size_t)(s0 + l15) * 8 + 4 + g];
    kb10 = kch[(size_t)(s0 + 16 + l15) * 8 + g];
    kb11 = kch[(size_t)(s0 + 16 + l15) * 8 + 4 + g];
    bv0 = *(const bf16x8*)&vch[((size_t)(start * 64 + l15)) * 32 + g * 8];
    bv1 = *(const bf16x8*)&vch[((size_t)(start * 64 + 16 + l15)) * 32 + g * 8];
    bv2 = *(const bf16x8*)&vch[((size_t)(start * 64 + 32 + l15)) * 32 + g * 8];
    bv3 = *(const bf16x8*)&vch[((size_t)(start * 64 + 48 + l15)) * 32 + g * 8];
  }

  for (int tt = start; tt < end; ++tt) {
    int s0 = tt * 32;
    f32x4 sa0, sa1;
    sa0 = 0; sa1 = 0;
    sa0 = mfma16(aq0, kb00, sa0);
    sa0 = mfma16(aq1, kb01, sa0);
    sa1 = mfma16(aq0, kb10, sa1);
    sa1 = mfma16(aq1, kb11, sa1);

    // T14: issue next tile's 8 loads now; softmax+PV hides their latency
    bf16x8 nk00, nk01, nk10, nk11, nv0, nv1, nv2, nv3;
    bool more = (tt + 1 < end);
    if (more) {
      int s1 = (tt + 1) * 32;
      nk00 = kch[(size_t)(s1 + l15) * 8 + g];
      nk01 = kch[(size_t)(s1 + l15) * 8 + 4 + g];
      nk10 = kch[(size_t)(s1 + 16 + l15) * 8 + g];
      nk11 = kch[(size_t)(s1 + 16 + l15) * 8 + 4 + g];
      int t1 = (tt + 1) * 64;
      nv0 = *(const bf16x8*)&vch[((size_t)(t1 + l15)) * 32 + g * 8];
      nv1 = *(const bf16x8*)&vch[((size_t)(t1 + 16 + l15)) * 32 + g * 8];
      nv2 = *(const bf16x8*)&vch[((size_t)(t1 + 32 + l15)) * 32 + g * 8];
      nv3 = *(const bf16x8*)&vch[((size_t)(t1 + 48 + l15)) * 32 + g * 8];
    }

#pragma unroll
    for (int vv = 0; vv < 4; ++vv) {
      int t = t_base + g * 4 + vv;
      float v0 = (s0 + l15 <= t) ? sa0[vv] : NEGB;
      float v1 = (s0 + 16 + l15 <= t) ? sa1[vv] : NEGB;
      float rm = fmaxf(v0, v1);
#pragma unroll
      for (int off = 8; off >= 1; off >>= 1)
        rm = fmaxf(rm, __shfl_xor(rm, off));
      float mn = fmaxf(m[vv], rm);
      float corr = __expf(m[vv] - mn);
      float p0 = (v0 == NEGB) ? 0.f : __expf(v0 - mn);  // all-masked tile guard
      float p1 = (v1 == NEGB) ? 0.f : __expf(v1 - mn);
      float rs = p0 + p1;
#pragma unroll
      for (int off = 8; off >= 1; off >>= 1) rs += __shfl_xor(rs, off);
      l[vv] = l[vv] * corr + rs;
      m[vv] = mn;
#pragma unroll
      for (int nt = 0; nt < 4; ++nt) o[nt][vv] *= corr;
      pL[w][g * 4 + vv][l15] = f2bf(p0);
      pL[w][g * 4 + vv][16 + l15] = f2bf(p1);
    }
    bf16x8 ap = *(const bf16x8*)&pL[w][l15][g * 8];
    o[0] = mfma16(ap, bv0, o[0]);
    o[1] = mfma16(ap, bv1, o[1]);
    o[2] = mfma16(ap, bv2, o[2]);
    o[3] = mfma16(ap, bv3, o[3]);
    if (more) {
      kb00 = nk00; kb01 = nk01; kb10 = nk10; kb11 = nk11;
      bv0 = nv0; bv1 = nv1; bv2 = nv2; bv3 = nv3;
    }
  }

  __syncthreads();
#pragma unroll
  for (int nt = 0; nt < 4; ++nt)
#pragma unroll
    for (int vv = 0; vv < 4; ++vv)
      oP[j][r][g * 4 + vv][nt * 16 + l15] = f2bf(o[nt][vv]);
  if (l15 == 0) {
#pragma unroll
    for (int vv = 0; vv < 4; ++vv) {
      mP[j][r][g * 4 + vv] = m[vv];
      lP[j][r][g * 4 + vv] = l[vv];
    }
  }
  __syncthreads();

  if (w < 2) {  // merge wave r=w: 16 rows x 64 cols, 4-way j-merge
    int len = lengths[b];
#pragma unroll 4
    for (int row = 0; row < 16; ++row) {
      float m0 = mP[0][w][row], m1 = mP[1][w][row];
      float m2 = mP[2][w][row], m3 = mP[3][w][row];
      float ms = fmaxf(fmaxf(m0, m1), fmaxf(m2, m3));
      float e0 = __expf(m0 - ms), e1 = __expf(m1 - ms);
      float e2 = __expf(m2 - ms), e3 = __expf(m3 - ms);
      float ls = lP[0][w][row] * e0 + lP[1][w][row] * e1 +
                 lP[2][w][row] * e2 + lP[3][w][row] * e3;
      float ov = bf2f(oP[0][w][row][lane]) * e0 +
                 bf2f(oP[1][w][row][lane]) * e1 +
                 bf2f(oP[2][w][row][lane]) * e2 +
                 bf2f(oP[3][w][row][lane]) * e3;
      float val = ov / ls;
      int t = t0 + w * 16 + row;
      if (t >= len) val = vmsum[b * 64 + lane] * (1.0f / T_SEQ);  // pad row
      Out[((size_t)b * T_SEQ + t) * 64 + lane] = val;
    }
  }
}

extern "C" void kernel_launch(void* const* d_in, const int* in_sizes, int n_in,
                              void* d_out, int out_size, void* d_ws,
                              size_t ws_size, hipStream_t stream) {
  const float* V = (const float*)d_in[0];
  const float* K = (const float*)d_in[1];
  const float* Q = (const float*)d_in[2];
  const float* Wq = (const float*)d_in[3];
  const float* Wk = (const float*)d_in[4];
  const float* Wv = (const float*)d_in[5];
  const unsigned char* mask = (const unsigned char*)d_in[6];
  float* O = (float*)d_out;
  char* ws = (char*)d_ws;

  unsigned short* wt = (unsigned short*)(ws);                        // 384 KiB
  unsigned short* qb = (unsigned short*)(ws + 393216);               // 2 MiB
  unsigned short* kb = (unsigned short*)(ws + 393216 + 2097152);     // 2 MiB
  unsigned short* vTb = (unsigned short*)(ws + 393216 + 2 * 2097152);// 2 MiB
  float* vmsum = (float*)(ws + 393216 + 3 * 2097152);                // 2 KiB
  int* lengths = (int*)(ws + 393216 + 3 * 2097152 + 2048);

  hipMemsetAsync(vmsum, 0, 512 * sizeof(float), stream);
  wt_k<<<768, 256, 0, stream>>>(Wq, Wk, Wv, wt);
  meta_k<<<NB, 256, 0, stream>>>(mask, lengths);
  proj_k<<<dim3(256, 3), 512, 0, stream>>>(Q, K, V, wt, qb, kb, vTb, vmsum);
  attn_k<<<512, 512, 0, stream>>>(qb, kb, vTb, vmsum, lengths, O);
}

// Round 12
// 94.868 us; speedup vs baseline: 1.0197x; 1.0197x over previous
//
#include <hip/hip_runtime.h>
#include <hip/hip_bf16.h>

typedef short bf16x8 __attribute__((ext_vector_type(8)));
typedef float f32x4 __attribute__((ext_vector_type(4)));
typedef unsigned int u32;
typedef u32 u32x4 __attribute__((ext_vector_type(4)));

#define T_SEQ 2048
#define NB 8
#define NEGB (-1e30f)

__device__ inline unsigned short f2bf(float f) {
  unsigned u = __builtin_bit_cast(unsigned, f);
  u += 0x7FFFu + ((u >> 16) & 1u);   // round-to-nearest-even
  return (unsigned short)(u >> 16);
}
__device__ inline float bf2f(unsigned short h) {
  unsigned u = ((unsigned)h) << 16;
  return __builtin_bit_cast(float, u);
}
__device__ inline u32 cvt2(float a, float b) {  // v_cvt_pk_bf16_f32 via HIP
  __hip_bfloat162 h = __float22bfloat162_rn(make_float2(a, b));
  u32 r;
  __builtin_memcpy(&r, &h, 4);
  return r;
}
__device__ inline bf16x8 pack8(float4 a, float4 b) {
  u32x4 p;
  p[0] = cvt2(a.x, a.y);
  p[1] = cvt2(a.z, a.w);
  p[2] = cvt2(b.x, b.y);
  p[3] = cvt2(b.z, b.w);
  return __builtin_bit_cast(bf16x8, p);
}
__device__ inline f32x4 mfma16(bf16x8 a, bf16x8 b, f32x4 c) {
  return __builtin_amdgcn_mfma_f32_16x16x32_bf16(a, b, c, 0, 0, 0);
}
// async 16B global -> LDS (DMA). ldsptr wave-uniform; lane l lands at +l*16.
__device__ __forceinline__ void gl_lds16(const void* g, void* l) {
  __builtin_amdgcn_global_load_lds(
      (const __attribute__((address_space(1))) void*)g,
      (__attribute__((address_space(3))) void*)l, 16, 0, 0);
}
// non-temporal variant: aux=2 -> 'nt' cpol (stream past L2/L3, no allocate).
// X is 192MB read-once-per-launch; NT avoids the L3 eviction-scatter regime
// (R11 verified: proj 79 -> 41us, 2.4-2.7 TB/s).
__device__ __forceinline__ void gl_lds16_nt(const void* g, void* l) {
  __builtin_amdgcn_global_load_lds(
      (const __attribute__((address_space(1))) void*)g,
      (__attribute__((address_space(3))) void*)l, 16, 0, 2);
}

// ---- meta: pad_mask dtype detect + lengths + vmsum zeroing ----------------
// (zeroing vmsum here replaces hipMemsetAsync, whose graph fill node cost
//  40.6us/replay — R11 counters)
__global__ void meta_k(const unsigned char* m, int* lengths, float* vmsum) {
  int b = blockIdx.x, tid = threadIdx.x;
  if (tid < 64) vmsum[b * 64 + tid] = 0.f;  // stream-ordered before proj_k
  int lo = 0, lb = 0;
  for (int i = tid; i < NB * T_SEQ; i += 256) {
    int v = (m[i] != 0);
    lo += v;
    if (i & 3) lb += v;
  }
  for (int off = 32; off >= 1; off >>= 1) {
    lo += __shfl_xor(lo, off);
    lb += __shfl_xor(lb, off);
  }
  __shared__ int s0[4], s1[4], ws2[4];
  if ((tid & 63) == 0) { s0[tid >> 6] = lo; s1[tid >> 6] = lb; }
  __syncthreads();
  int ones = s0[0] + s0[1] + s0[2] + s0[3];
  int bad = s1[0] + s1[1] + s1[2] + s1[3];
  int flag = (ones > 0 && bad == 0);  // 1 => int32 storage
  int cnt = 0;
  if (flag) {
    const int* mi = (const int*)m;
    for (int t = tid; t < T_SEQ; t += 256) cnt += (mi[b * T_SEQ + t] == 0);
  } else {
    for (int t = tid; t < T_SEQ; t += 256) cnt += (m[b * T_SEQ + t] == 0);
  }
  for (int off = 32; off >= 1; off >>= 1) cnt += __shfl_xor(cnt, off);
  __syncthreads();
  if ((tid & 63) == 0) ws2[tid >> 6] = cnt;
  __syncthreads();
  if (tid == 0) lengths[b] = ws2[0] + ws2[1] + ws2[2] + ws2[3];
}

// WT[mi][n][k] (bf16) = W_mi[k][n]
__global__ void wt_k(const float* Wq, const float* Wk, const float* Wv,
                     unsigned short* wt) {
  int e = blockIdx.x * 256 + threadIdx.x;
  if (e >= 3 * 64 * 1024) return;
  int mi = e >> 16;
  int rem = e & 65535;
  int kk = rem & 1023, n = rem >> 10;
  const float* W = (mi == 0) ? Wq : (mi == 1) ? Wk : Wv;
  wt[e] = f2bf(W[kk * 64 + n]);
}

// Projection GEMM (R6 structure + R11 NT loads — at ~41us, do not restructure).
__global__ __launch_bounds__(512, 4) void proj_k(
    const float* Q, const float* K, const float* V, const unsigned short* wt,
    unsigned short* qo, unsigned short* ko, unsigned short* vTb, float* vmsum) {
  __shared__ float xs[2][4096];          // 16 KB x2: [row][k] f32 (pre-swizzled)
  __shared__ unsigned short wss[2][4096];// 8 KB x2: [n][k] bf16 (pre-swizzled)
  int mi = blockIdx.y;
  const float* X = (mi == 0) ? Q : (mi == 1) ? K : V;
  const unsigned short* wtm = wt + mi * 65536;
  int tid = threadIdx.x;
  int w = tid >> 6, lane = tid & 63, l15 = lane & 15, g = lane >> 4;
  int wr = w >> 1, wc = w & 1;
  int r0b = blockIdx.x * 64;

  // staging addresses: per wave exactly 3 gl_lds instrs/chunk
  int segA = w * 2;
  int rowA0 = segA * 4 + (lane >> 4);
  int rowA1 = rowA0 + 4;
  int colA0 = ((lane & 15) ^ (rowA0 & 15)) * 4;
  int colA1 = ((lane & 15) ^ (rowA1 & 15)) * 4;
  const float* srcA0 = X + (size_t)(r0b + rowA0) * 1024 + colA0;
  const float* srcA1 = X + (size_t)(r0b + rowA1) * 1024 + colA1;
  int nW = w * 8 + (lane >> 3);
  int skW = ((lane & 7) ^ (nW & 7)) * 8;
  const unsigned short* srcW = wtm + (size_t)nW * 1024 + skW;

  f32x4 acc[2];
  acc[0] = 0; acc[1] = 0;

#define STAGE(buf, kc2)                                          \
  do {                                                           \
    gl_lds16_nt(srcA0 + (kc2) * 64, &xs[buf][segA * 256]);       \
    gl_lds16_nt(srcA1 + (kc2) * 64, &xs[buf][segA * 256 + 256]); \
    gl_lds16(srcW + (kc2) * 64, &wss[buf][w * 512]);             \
  } while (0)

  STAGE(0, 0);  // prologue: chunk 0 in flight

  int arow = wr * 16 + l15;
  for (int kc = 0; kc < 16; ++kc) {
    int cur = kc & 1;
    if (kc < 15) {
      STAGE(cur ^ 1, kc + 1);  // overwrite-safe: post-compute barrier of kc-1
      // wait chunk kc only; chunk kc+1's 3 loads REMAIN IN FLIGHT (T4)
      asm volatile("s_waitcnt vmcnt(3)" ::: "memory");
    } else {
      asm volatile("s_waitcnt vmcnt(0)" ::: "memory");
    }
    __builtin_amdgcn_s_barrier();  // raw: no compiler vmcnt(0) drain
#pragma unroll
    for (int ks = 0; ks < 2; ++ks) {
      int lb0 = ks * 8 + g * 2;
      float4 fa = *(const float4*)&xs[cur][arow * 64 + ((lb0 ^ l15) * 4)];
      float4 fb = *(const float4*)&xs[cur][arow * 64 + (((lb0 + 1) ^ l15) * 4)];
      bf16x8 a = pack8(fa, fb);
#pragma unroll
      for (int nt = 0; nt < 2; ++nt) {
        int nrow = wc * 32 + nt * 16 + l15;
        bf16x8 bb = *(const bf16x8*)
            &wss[cur][nrow * 64 + (((ks * 4 + g) ^ (l15 & 7)) * 8)];
        acc[nt] = mfma16(a, bb, acc[nt]);
      }
    }
    if (kc < 15) {
      // my LDS reads must retire before others' next STAGE overwrites
      asm volatile("s_waitcnt lgkmcnt(0)" ::: "memory");
      __builtin_amdgcn_s_barrier();
    }
  }
#undef STAGE

  // D layout: col = lane&15, row = g*4 + vv
#pragma unroll
  for (int nt = 0; nt < 2; ++nt)
#pragma unroll
    for (int vv = 0; vv < 4; ++vv) {
      int rr = r0b + wr * 16 + g * 4 + vv;
      int c = wc * 32 + nt * 16 + l15;
      float val = acc[nt][vv];
      if (mi == 0) {
        qo[(size_t)rr * 64 + c] = f2bf(val * 0.03125f);  // fold C^-0.5
      } else if (mi == 1) {
        ko[(size_t)rr * 64 + c] = f2bf(val);
      } else {
        int bb = rr >> 11, ts = rr & 2047;
        // tile-blocked vT: [b][t/32][d][t%32]
        vTb[(((size_t)bb * 64 + (ts >> 5)) * 64 + c) * 32 + (ts & 31)] =
            f2bf(val);
      }
    }

  if (mi == 2) {  // fold v column-sums into vmsum[b][d] (replaces vmean_k)
    float ps0 = acc[0][0] + acc[0][1] + acc[0][2] + acc[0][3];
    float ps1 = acc[1][0] + acc[1][1] + acc[1][2] + acc[1][3];
    __syncthreads();  // K-loop LDS fully retired; reuse xs as scratch
    float* rb = (float*)xs;  // [64 cols][16 contributors]
    rb[(wc * 32 + l15) * 16 + (wr * 4 + g)] = ps0;
    rb[(wc * 32 + 16 + l15) * 16 + (wr * 4 + g)] = ps1;
    __syncthreads();
    if (tid < 64) {
      float s = 0.f;
#pragma unroll
      for (int i = 0; i < 16; ++i) s += rb[tid * 16 + i];
      atomicAdd(&vmsum[(blockIdx.x >> 5) * 64 + tid], s);
    }
  }
}

// Flash attention: 512 threads = 8 waves = 4 key-chunks x 2 row-groups;
// 32 q-rows per block; 512 blocks (2/CU), complementary work pairing.
// T14: K/V frags for tile tt+1 issued right after tt's QK MFMAs.
__global__ __launch_bounds__(512, 4) void attn_k(
    const unsigned short* q, const unsigned short* k, const unsigned short* vTb,
    const float* vmsum, const int* lengths, float* Out) {
  __shared__ unsigned short pL[8][16][40];      // per-wave P round-trip
  __shared__ unsigned short oP[4][2][16][64];   // bf16 partial O [j][r][row][col]
  __shared__ float mP[4][2][16], lP[4][2][16];

  // complementary work pairing: co-resident blocks sum to ~constant work
  int id = blockIdx.x;
  int raw = id & 63, b = id >> 6;
  int xx = (raw + 8 * b) & 63;
  int tile = (xx < 32) ? xx : 95 - xx;   // bijective on 0..63
  int t0 = tile * 32;

  int tid = threadIdx.x;
  int w = tid >> 6, lane = tid & 63;
  int j = w >> 1, r = w & 1;
  int l15 = lane & 15, g = lane >> 4;
  int t_base = t0 + r * 16;

  const bf16x8* qrow =
      (const bf16x8*)(q + ((size_t)b * T_SEQ + t_base + l15) * 64);
  bf16x8 aq0 = qrow[g];
  bf16x8 aq1 = qrow[4 + g];

  f32x4 o[4];
  float m[4], l[4];
#pragma unroll
  for (int i = 0; i < 4; ++i) { o[i] = 0; m[i] = NEGB; l[i] = 0.f; }

  const bf16x8* kch = (const bf16x8*)k + (size_t)b * T_SEQ * 8;
  const unsigned short* vch = vTb + (size_t)b * 131072;

  // balanced contiguous tile-chunks over this block's NT key-tiles
  int NT = tile + 1;
  int qn = NT >> 2, rem = NT & 3;
  int start = j * qn + (j < rem ? j : rem);
  int end = start + qn + (j < rem ? 1 : 0);
  int capw = ((t_base + 15) >> 5) + 1;
  if (end > capw) end = capw;

  bf16x8 kb00, kb01, kb10, kb11, bv0, bv1, bv2, bv3;
  if (start < end) {  // prologue loads for first tile
    int s0 = start * 32;
    kb00 = kch[(size_t)(s0 + l15) * 8 + g];
    kb01 = kch[(size_t)(s0 + l15) * 8 + 4 + g];
    kb10 = kch[(size_t)(s0 + 16 + l15) * 8 + g];
    kb11 = kch[(size_t)(s0 + 16 + l15) * 8 + 4 + g];
    bv0 = *(const bf16x8*)&vch[((size_t)(start * 64 + l15)) * 32 + g * 8];
    bv1 = *(const bf16x8*)&vch[((size_t)(start * 64 + 16 + l15)) * 32 + g * 8];
    bv2 = *(const bf16x8*)&vch[((size_t)(start * 64 + 32 + l15)) * 32 + g * 8];
    bv3 = *(const bf16x8*)&vch[((size_t)(start * 64 + 48 + l15)) * 32 + g * 8];
  }

  for (int tt = start; tt < end; ++tt) {
    int s0 = tt * 32;
    f32x4 sa0, sa1;
    sa0 = 0; sa1 = 0;
    sa0 = mfma16(aq0, kb00, sa0);
    sa0 = mfma16(aq1, kb01, sa0);
    sa1 = mfma16(aq0, kb10, sa1);
    sa1 = mfma16(aq1, kb11, sa1);

    // T14: issue next tile's 8 loads now; softmax+PV hides their latency
    bf16x8 nk00, nk01, nk10, nk11, nv0, nv1, nv2, nv3;
    bool more = (tt + 1 < end);
    if (more) {
      int s1 = (tt + 1) * 32;
      nk00 = kch[(size_t)(s1 + l15) * 8 + g];
      nk01 = kch[(size_t)(s1 + l15) * 8 + 4 + g];
      nk10 = kch[(size_t)(s1 + 16 + l15) * 8 + g];
      nk11 = kch[(size_t)(s1 + 16 + l15) * 8 + 4 + g];
      int t1 = (tt + 1) * 64;
      nv0 = *(const bf16x8*)&vch[((size_t)(t1 + l15)) * 32 + g * 8];
      nv1 = *(const bf16x8*)&vch[((size_t)(t1 + 16 + l15)) * 32 + g * 8];
      nv2 = *(const bf16x8*)&vch[((size_t)(t1 + 32 + l15)) * 32 + g * 8];
      nv3 = *(const bf16x8*)&vch[((size_t)(t1 + 48 + l15)) * 32 + g * 8];
    }

#pragma unroll
    for (int vv = 0; vv < 4; ++vv) {
      int t = t_base + g * 4 + vv;
      float v0 = (s0 + l15 <= t) ? sa0[vv] : NEGB;
      float v1 = (s0 + 16 + l15 <= t) ? sa1[vv] : NEGB;
      float rm = fmaxf(v0, v1);
#pragma unroll
      for (int off = 8; off >= 1; off >>= 1)
        rm = fmaxf(rm, __shfl_xor(rm, off));
      float mn = fmaxf(m[vv], rm);
      float corr = __expf(m[vv] - mn);
      float p0 = (v0 == NEGB) ? 0.f : __expf(v0 - mn);  // all-masked tile guard
      float p1 = (v1 == NEGB) ? 0.f : __expf(v1 - mn);
      float rs = p0 + p1;
#pragma unroll
      for (int off = 8; off >= 1; off >>= 1) rs += __shfl_xor(rs, off);
      l[vv] = l[vv] * corr + rs;
      m[vv] = mn;
#pragma unroll
      for (int nt = 0; nt < 4; ++nt) o[nt][vv] *= corr;
      pL[w][g * 4 + vv][l15] = f2bf(p0);
      pL[w][g * 4 + vv][16 + l15] = f2bf(p1);
    }
    bf16x8 ap = *(const bf16x8*)&pL[w][l15][g * 8];
    o[0] = mfma16(ap, bv0, o[0]);
    o[1] = mfma16(ap, bv1, o[1]);
    o[2] = mfma16(ap, bv2, o[2]);
    o[3] = mfma16(ap, bv3, o[3]);
    if (more) {
      kb00 = nk00; kb01 = nk01; kb10 = nk10; kb11 = nk11;
      bv0 = nv0; bv1 = nv1; bv2 = nv2; bv3 = nv3;
    }
  }

  __syncthreads();
#pragma unroll
  for (int nt = 0; nt < 4; ++nt)
#pragma unroll
    for (int vv = 0; vv < 4; ++vv)
      oP[j][r][g * 4 + vv][nt * 16 + l15] = f2bf(o[nt][vv]);
  if (l15 == 0) {
#pragma unroll
    for (int vv = 0; vv < 4; ++vv) {
      mP[j][r][g * 4 + vv] = m[vv];
      lP[j][r][g * 4 + vv] = l[vv];
    }
  }
  __syncthreads();

  if (w < 2) {  // merge wave r=w: 16 rows x 64 cols, 4-way j-merge
    int len = lengths[b];
#pragma unroll 4
    for (int row = 0; row < 16; ++row) {
      float m0 = mP[0][w][row], m1 = mP[1][w][row];
      float m2 = mP[2][w][row], m3 = mP[3][w][row];
      float ms = fmaxf(fmaxf(m0, m1), fmaxf(m2, m3));
      float e0 = __expf(m0 - ms), e1 = __expf(m1 - ms);
      float e2 = __expf(m2 - ms), e3 = __expf(m3 - ms);
      float ls = lP[0][w][row] * e0 + lP[1][w][row] * e1 +
                 lP[2][w][row] * e2 + lP[3][w][row] * e3;
      float ov = bf2f(oP[0][w][row][lane]) * e0 +
                 bf2f(oP[1][w][row][lane]) * e1 +
                 bf2f(oP[2][w][row][lane]) * e2 +
                 bf2f(oP[3][w][row][lane]) * e3;
      float val = ov / ls;
      int t = t0 + w * 16 + row;
      if (t >= len) val = vmsum[b * 64 + lane] * (1.0f / T_SEQ);  // pad row
      Out[((size_t)b * T_SEQ + t) * 64 + lane] = val;
    }
  }
}

extern "C" void kernel_launch(void* const* d_in, const int* in_sizes, int n_in,
                              void* d_out, int out_size, void* d_ws,
                              size_t ws_size, hipStream_t stream) {
  const float* V = (const float*)d_in[0];
  const float* K = (const float*)d_in[1];
  const float* Q = (const float*)d_in[2];
  const float* Wq = (const float*)d_in[3];
  const float* Wk = (const float*)d_in[4];
  const float* Wv = (const float*)d_in[5];
  const unsigned char* mask = (const unsigned char*)d_in[6];
  float* O = (float*)d_out;
  char* ws = (char*)d_ws;

  unsigned short* wt = (unsigned short*)(ws);                        // 384 KiB
  unsigned short* qb = (unsigned short*)(ws + 393216);               // 2 MiB
  unsigned short* kb = (unsigned short*)(ws + 393216 + 2097152);     // 2 MiB
  unsigned short* vTb = (unsigned short*)(ws + 393216 + 2 * 2097152);// 2 MiB
  float* vmsum = (float*)(ws + 393216 + 3 * 2097152);                // 2 KiB
  int* lengths = (int*)(ws + 393216 + 3 * 2097152 + 2048);

  wt_k<<<768, 256, 0, stream>>>(Wq, Wk, Wv, wt);
  meta_k<<<NB, 256, 0, stream>>>(mask, lengths, vmsum);
  proj_k<<<dim3(256, 3), 512, 0, stream>>>(Q, K, V, wt, qb, kb, vTb, vmsum);
  attn_k<<<512, 512, 0, stream>>>(qb, kb, vTb, vmsum, lengths, O);
}

// Round 13
// 82.540 us; speedup vs baseline: 1.1720x; 1.1494x over previous
//
#include <hip/hip_runtime.h>
#include <hip/hip_bf16.h>

typedef short bf16x8 __attribute__((ext_vector_type(8)));
typedef float f32x4 __attribute__((ext_vector_type(4)));
typedef unsigned int u32;
typedef u32 u32x4 __attribute__((ext_vector_type(4)));

#define T_SEQ 2048
#define NB 8
#define NEGB (-1e30f)

__device__ inline unsigned short f2bf(float f) {
  unsigned u = __builtin_bit_cast(unsigned, f);
  u += 0x7FFFu + ((u >> 16) & 1u);   // round-to-nearest-even
  return (unsigned short)(u >> 16);
}
__device__ inline float bf2f(unsigned short h) {
  unsigned u = ((unsigned)h) << 16;
  return __builtin_bit_cast(float, u);
}
__device__ inline u32 cvt2(float a, float b) {  // v_cvt_pk_bf16_f32 via HIP
  __hip_bfloat162 h = __float22bfloat162_rn(make_float2(a, b));
  u32 r;
  __builtin_memcpy(&r, &h, 4);
  return r;
}
__device__ inline bf16x8 pack8(float4 a, float4 b) {
  u32x4 p;
  p[0] = cvt2(a.x, a.y);
  p[1] = cvt2(a.z, a.w);
  p[2] = cvt2(b.x, b.y);
  p[3] = cvt2(b.z, b.w);
  return __builtin_bit_cast(bf16x8, p);
}
__device__ inline f32x4 mfma16(bf16x8 a, bf16x8 b, f32x4 c) {
  return __builtin_amdgcn_mfma_f32_16x16x32_bf16(a, b, c, 0, 0, 0);
}
// async 16B global -> LDS (DMA). ldsptr wave-uniform; lane l lands at +l*16.
// NOTE: aux=2 ("NT") variant REVERTED — it halved proj under rocprof's
// flushed-cache serialized replays but cost +5-7us in the timed regime
// (R10=90.0 no-NT vs R12=94.9 NT, memset-free). Timed regime is the score.
__device__ __forceinline__ void gl_lds16(const void* g, void* l) {
  __builtin_amdgcn_global_load_lds(
      (const __attribute__((address_space(1))) void*)g,
      (__attribute__((address_space(3))) void*)l, 16, 0, 0);
}

// ---- prep: fused WT transpose (blocks 0..767) + mask meta (blocks 768..775)
// WT[mi][n][k] (bf16) = W_mi[k][n]; meta = dtype detect + lengths + vmsum=0.
__global__ void prep_k(const float* Wq, const float* Wk, const float* Wv,
                       unsigned short* wt, const unsigned char* m,
                       int* lengths, float* vmsum) {
  int tid = threadIdx.x;
  if (blockIdx.x < 768) {
    int e = blockIdx.x * 256 + tid;  // 768*256 == 3*65536 exactly
    int mi = e >> 16;
    int rem = e & 65535;
    int kk = rem & 1023, n = rem >> 10;
    const float* W = (mi == 0) ? Wq : (mi == 1) ? Wk : Wv;
    wt[e] = f2bf(W[kk * 64 + n]);
    return;
  }
  int b = blockIdx.x - 768;
  if (tid < 64) vmsum[b * 64 + tid] = 0.f;  // stream-ordered before proj_k
  // int32 0/1 storage has 1-bytes ONLY at byte%4==0; bool padding always has
  // a misaligned 1. ones==0 -> both interpretations agree anyway.
  int lo = 0, lb = 0;
  for (int i = tid; i < NB * T_SEQ; i += 256) {
    int v = (m[i] != 0);
    lo += v;
    if (i & 3) lb += v;
  }
  for (int off = 32; off >= 1; off >>= 1) {
    lo += __shfl_xor(lo, off);
    lb += __shfl_xor(lb, off);
  }
  __shared__ int s0[4], s1[4], ws2[4];
  if ((tid & 63) == 0) { s0[tid >> 6] = lo; s1[tid >> 6] = lb; }
  __syncthreads();
  int ones = s0[0] + s0[1] + s0[2] + s0[3];
  int bad = s1[0] + s1[1] + s1[2] + s1[3];
  int flag = (ones > 0 && bad == 0);  // 1 => int32 storage
  int cnt = 0;
  if (flag) {
    const int* mi2 = (const int*)m;
    for (int t = tid; t < T_SEQ; t += 256) cnt += (mi2[b * T_SEQ + t] == 0);
  } else {
    for (int t = tid; t < T_SEQ; t += 256) cnt += (m[b * T_SEQ + t] == 0);
  }
  for (int off = 32; off >= 1; off >>= 1) cnt += __shfl_xor(cnt, off);
  __syncthreads();
  if ((tid & 63) == 0) ws2[tid >> 6] = cnt;
  __syncthreads();
  if (tid == 0) lengths[b] = ws2[0] + ws2[1] + ws2[2] + ws2[3];
}

// Projection GEMM (R6 structure — timed-regime best; L3-capacity-bound).
__global__ __launch_bounds__(512, 4) void proj_k(
    const float* Q, const float* K, const float* V, const unsigned short* wt,
    unsigned short* qo, unsigned short* ko, unsigned short* vTb, float* vmsum) {
  __shared__ float xs[2][4096];          // 16 KB x2: [row][k] f32 (pre-swizzled)
  __shared__ unsigned short wss[2][4096];// 8 KB x2: [n][k] bf16 (pre-swizzled)
  int mi = blockIdx.y;
  const float* X = (mi == 0) ? Q : (mi == 1) ? K : V;
  const unsigned short* wtm = wt + mi * 65536;
  int tid = threadIdx.x;
  int w = tid >> 6, lane = tid & 63, l15 = lane & 15, g = lane >> 4;
  int wr = w >> 1, wc = w & 1;
  int r0b = blockIdx.x * 64;

  // staging addresses: per wave exactly 3 gl_lds instrs/chunk
  int segA = w * 2;
  int rowA0 = segA * 4 + (lane >> 4);
  int rowA1 = rowA0 + 4;
  int colA0 = ((lane & 15) ^ (rowA0 & 15)) * 4;
  int colA1 = ((lane & 15) ^ (rowA1 & 15)) * 4;
  const float* srcA0 = X + (size_t)(r0b + rowA0) * 1024 + colA0;
  const float* srcA1 = X + (size_t)(r0b + rowA1) * 1024 + colA1;
  int nW = w * 8 + (lane >> 3);
  int skW = ((lane & 7) ^ (nW & 7)) * 8;
  const unsigned short* srcW = wtm + (size_t)nW * 1024 + skW;

  f32x4 acc[2];
  acc[0] = 0; acc[1] = 0;

#define STAGE(buf, kc2)                                          \
  do {                                                           \
    gl_lds16(srcA0 + (kc2) * 64, &xs[buf][segA * 256]);          \
    gl_lds16(srcA1 + (kc2) * 64, &xs[buf][segA * 256 + 256]);    \
    gl_lds16(srcW + (kc2) * 64, &wss[buf][w * 512]);             \
  } while (0)

  STAGE(0, 0);  // prologue: chunk 0 in flight

  int arow = wr * 16 + l15;
  for (int kc = 0; kc < 16; ++kc) {
    int cur = kc & 1;
    if (kc < 15) {
      STAGE(cur ^ 1, kc + 1);  // overwrite-safe: post-compute barrier of kc-1
      // wait chunk kc only; chunk kc+1's 3 loads REMAIN IN FLIGHT (T4)
      asm volatile("s_waitcnt vmcnt(3)" ::: "memory");
    } else {
      asm volatile("s_waitcnt vmcnt(0)" ::: "memory");
    }
    __builtin_amdgcn_s_barrier();  // raw: no compiler vmcnt(0) drain
#pragma unroll
    for (int ks = 0; ks < 2; ++ks) {
      int lb0 = ks * 8 + g * 2;
      float4 fa = *(const float4*)&xs[cur][arow * 64 + ((lb0 ^ l15) * 4)];
      float4 fb = *(const float4*)&xs[cur][arow * 64 + (((lb0 + 1) ^ l15) * 4)];
      bf16x8 a = pack8(fa, fb);
#pragma unroll
      for (int nt = 0; nt < 2; ++nt) {
        int nrow = wc * 32 + nt * 16 + l15;
        bf16x8 bb = *(const bf16x8*)
            &wss[cur][nrow * 64 + (((ks * 4 + g) ^ (l15 & 7)) * 8)];
        acc[nt] = mfma16(a, bb, acc[nt]);
      }
    }
    if (kc < 15) {
      // my LDS reads must retire before others' next STAGE overwrites
      asm volatile("s_waitcnt lgkmcnt(0)" ::: "memory");
      __builtin_amdgcn_s_barrier();
    }
  }
#undef STAGE

  // D layout: col = lane&15, row = g*4 + vv
#pragma unroll
  for (int nt = 0; nt < 2; ++nt)
#pragma unroll
    for (int vv = 0; vv < 4; ++vv) {
      int rr = r0b + wr * 16 + g * 4 + vv;
      int c = wc * 32 + nt * 16 + l15;
      float val = acc[nt][vv];
      if (mi == 0) {
        qo[(size_t)rr * 64 + c] = f2bf(val * 0.03125f);  // fold C^-0.5
      } else if (mi == 1) {
        ko[(size_t)rr * 64 + c] = f2bf(val);
      } else {
        int bb = rr >> 11, ts = rr & 2047;
        // tile-blocked vT: [b][t/32][d][t%32]
        vTb[(((size_t)bb * 64 + (ts >> 5)) * 64 + c) * 32 + (ts & 31)] =
            f2bf(val);
      }
    }

  if (mi == 2) {  // fold v column-sums into vmsum[b][d] (replaces vmean_k)
    float ps0 = acc[0][0] + acc[0][1] + acc[0][2] + acc[0][3];
    float ps1 = acc[1][0] + acc[1][1] + acc[1][2] + acc[1][3];
    __syncthreads();  // K-loop LDS fully retired; reuse xs as scratch
    float* rb = (float*)xs;  // [64 cols][16 contributors]
    rb[(wc * 32 + l15) * 16 + (wr * 4 + g)] = ps0;
    rb[(wc * 32 + 16 + l15) * 16 + (wr * 4 + g)] = ps1;
    __syncthreads();
    if (tid < 64) {
      float s = 0.f;
#pragma unroll
      for (int i = 0; i < 16; ++i) s += rb[tid * 16 + i];
      atomicAdd(&vmsum[(blockIdx.x >> 5) * 64 + tid], s);
    }
  }
}

// Flash attention: 512 threads = 8 waves = 4 key-chunks x 2 row-groups;
// 32 q-rows per block; 512 blocks (2/CU), complementary work pairing.
// T14: K/V frags for tile tt+1 issued right after tt's QK MFMAs.
__global__ __launch_bounds__(512, 4) void attn_k(
    const unsigned short* q, const unsigned short* k, const unsigned short* vTb,
    const float* vmsum, const int* lengths, float* Out) {
  __shared__ unsigned short pL[8][16][40];      // per-wave P round-trip
  __shared__ unsigned short oP[4][2][16][64];   // bf16 partial O [j][r][row][col]
  __shared__ float mP[4][2][16], lP[4][2][16];

  // complementary work pairing: co-resident blocks sum to ~constant work
  int id = blockIdx.x;
  int raw = id & 63, b = id >> 6;
  int xx = (raw + 8 * b) & 63;
  int tile = (xx < 32) ? xx : 95 - xx;   // bijective on 0..63
  int t0 = tile * 32;

  int tid = threadIdx.x;
  int w = tid >> 6, lane = tid & 63;
  int j = w >> 1, r = w & 1;
  int l15 = lane & 15, g = lane >> 4;
  int t_base = t0 + r * 16;

  const bf16x8* qrow =
      (const bf16x8*)(q + ((size_t)b * T_SEQ + t_base + l15) * 64);
  bf16x8 aq0 = qrow[g];
  bf16x8 aq1 = qrow[4 + g];

  f32x4 o[4];
  float m[4], l[4];
#pragma unroll
  for (int i = 0; i < 4; ++i) { o[i] = 0; m[i] = NEGB; l[i] = 0.f; }

  const bf16x8* kch = (const bf16x8*)k + (size_t)b * T_SEQ * 8;
  const unsigned short* vch = vTb + (size_t)b * 131072;

  // balanced contiguous tile-chunks over this block's NT key-tiles
  int NT = tile + 1;
  int qn = NT >> 2, rem = NT & 3;
  int start = j * qn + (j < rem ? j : rem);
  int end = start + qn + (j < rem ? 1 : 0);
  int capw = ((t_base + 15) >> 5) + 1;
  if (end > capw) end = capw;

  bf16x8 kb00, kb01, kb10, kb11, bv0, bv1, bv2, bv3;
  if (start < end) {  // prologue loads for first tile
    int s0 = start * 32;
    kb00 = kch[(size_t)(s0 + l15) * 8 + g];
    kb01 = kch[(size_t)(s0 + l15) * 8 + 4 + g];
    kb10 = kch[(size_t)(s0 + 16 + l15) * 8 + g];
    kb11 = kch[(size_t)(s0 + 16 + l15) * 8 + 4 + g];
    bv0 = *(const bf16x8*)&vch[((size_t)(start * 64 + l15)) * 32 + g * 8];
    bv1 = *(const bf16x8*)&vch[((size_t)(start * 64 + 16 + l15)) * 32 + g * 8];
    bv2 = *(const bf16x8*)&vch[((size_t)(start * 64 + 32 + l15)) * 32 + g * 8];
    bv3 = *(const bf16x8*)&vch[((size_t)(start * 64 + 48 + l15)) * 32 + g * 8];
  }

  for (int tt = start; tt < end; ++tt) {
    int s0 = tt * 32;
    f32x4 sa0, sa1;
    sa0 = 0; sa1 = 0;
    sa0 = mfma16(aq0, kb00, sa0);
    sa0 = mfma16(aq1, kb01, sa0);
    sa1 = mfma16(aq0, kb10, sa1);
    sa1 = mfma16(aq1, kb11, sa1);

    // T14: issue next tile's 8 loads now; softmax+PV hides their latency
    bf16x8 nk00, nk01, nk10, nk11, nv0, nv1, nv2, nv3;
    bool more = (tt + 1 < end);
    if (more) {
      int s1 = (tt + 1) * 32;
      nk00 = kch[(size_t)(s1 + l15) * 8 + g];
      nk01 = kch[(size_t)(s1 + l15) * 8 + 4 + g];
      nk10 = kch[(size_t)(s1 + 16 + l15) * 8 + g];
      nk11 = kch[(size_t)(s1 + 16 + l15) * 8 + 4 + g];
      int t1 = (tt + 1) * 64;
      nv0 = *(const bf16x8*)&vch[((size_t)(t1 + l15)) * 32 + g * 8];
      nv1 = *(const bf16x8*)&vch[((size_t)(t1 + 16 + l15)) * 32 + g * 8];
      nv2 = *(const bf16x8*)&vch[((size_t)(t1 + 32 + l15)) * 32 + g * 8];
      nv3 = *(const bf16x8*)&vch[((size_t)(t1 + 48 + l15)) * 32 + g * 8];
    }

#pragma unroll
    for (int vv = 0; vv < 4; ++vv) {
      int t = t_base + g * 4 + vv;
      float v0 = (s0 + l15 <= t) ? sa0[vv] : NEGB;
      float v1 = (s0 + 16 + l15 <= t) ? sa1[vv] : NEGB;
      float rm = fmaxf(v0, v1);
#pragma unroll
      for (int off = 8; off >= 1; off >>= 1)
        rm = fmaxf(rm, __shfl_xor(rm, off));
      float mn = fmaxf(m[vv], rm);
      float corr = __expf(m[vv] - mn);
      float p0 = (v0 == NEGB) ? 0.f : __expf(v0 - mn);  // all-masked tile guard
      float p1 = (v1 == NEGB) ? 0.f : __expf(v1 - mn);
      float rs = p0 + p1;
#pragma unroll
      for (int off = 8; off >= 1; off >>= 1) rs += __shfl_xor(rs, off);
      l[vv] = l[vv] * corr + rs;
      m[vv] = mn;
#pragma unroll
      for (int nt = 0; nt < 4; ++nt) o[nt][vv] *= corr;
      pL[w][g * 4 + vv][l15] = f2bf(p0);
      pL[w][g * 4 + vv][16 + l15] = f2bf(p1);
    }
    bf16x8 ap = *(const bf16x8*)&pL[w][l15][g * 8];
    o[0] = mfma16(ap, bv0, o[0]);
    o[1] = mfma16(ap, bv1, o[1]);
    o[2] = mfma16(ap, bv2, o[2]);
    o[3] = mfma16(ap, bv3, o[3]);
    if (more) {
      kb00 = nk00; kb01 = nk01; kb10 = nk10; kb11 = nk11;
      bv0 = nv0; bv1 = nv1; bv2 = nv2; bv3 = nv3;
    }
  }

  __syncthreads();
#pragma unroll
  for (int nt = 0; nt < 4; ++nt)
#pragma unroll
    for (int vv = 0; vv < 4; ++vv)
      oP[j][r][g * 4 + vv][nt * 16 + l15] = f2bf(o[nt][vv]);
  if (l15 == 0) {
#pragma unroll
    for (int vv = 0; vv < 4; ++vv) {
      mP[j][r][g * 4 + vv] = m[vv];
      lP[j][r][g * 4 + vv] = l[vv];
    }
  }
  __syncthreads();

  if (w < 2) {  // merge wave r=w: 16 rows x 64 cols, 4-way j-merge
    int len = lengths[b];
#pragma unroll 4
    for (int row = 0; row < 16; ++row) {
      float m0 = mP[0][w][row], m1 = mP[1][w][row];
      float m2 = mP[2][w][row], m3 = mP[3][w][row];
      float ms = fmaxf(fmaxf(m0, m1), fmaxf(m2, m3));
      float e0 = __expf(m0 - ms), e1 = __expf(m1 - ms);
      float e2 = __expf(m2 - ms), e3 = __expf(m3 - ms);
      float ls = lP[0][w][row] * e0 + lP[1][w][row] * e1 +
                 lP[2][w][row] * e2 + lP[3][w][row] * e3;
      float ov = bf2f(oP[0][w][row][lane]) * e0 +
                 bf2f(oP[1][w][row][lane]) * e1 +
                 bf2f(oP[2][w][row][lane]) * e2 +
                 bf2f(oP[3][w][row][lane]) * e3;
      float val = ov / ls;
      int t = t0 + w * 16 + row;
      if (t >= len) val = vmsum[b * 64 + lane] * (1.0f / T_SEQ);  // pad row
      Out[((size_t)b * T_SEQ + t) * 64 + lane] = val;
    }
  }
}

extern "C" void kernel_launch(void* const* d_in, const int* in_sizes, int n_in,
                              void* d_out, int out_size, void* d_ws,
                              size_t ws_size, hipStream_t stream) {
  const float* V = (const float*)d_in[0];
  const float* K = (const float*)d_in[1];
  const float* Q = (const float*)d_in[2];
  const float* Wq = (const float*)d_in[3];
  const float* Wk = (const float*)d_in[4];
  const float* Wv = (const float*)d_in[5];
  const unsigned char* mask = (const unsigned char*)d_in[6];
  float* O = (float*)d_out;
  char* ws = (char*)d_ws;

  unsigned short* wt = (unsigned short*)(ws);                        // 384 KiB
  unsigned short* qb = (unsigned short*)(ws + 393216);               // 2 MiB
  unsigned short* kb = (unsigned short*)(ws + 393216 + 2097152);     // 2 MiB
  unsigned short* vTb = (unsigned short*)(ws + 393216 + 2 * 2097152);// 2 MiB
  float* vmsum = (float*)(ws + 393216 + 3 * 2097152);                // 2 KiB
  int* lengths = (int*)(ws + 393216 + 3 * 2097152 + 2048);

  prep_k<<<776, 256, 0, stream>>>(Wq, Wk, Wv, wt, mask, lengths, vmsum);
  proj_k<<<dim3(256, 3), 512, 0, stream>>>(Q, K, V, wt, qb, kb, vTb, vmsum);
  attn_k<<<512, 512, 0, stream>>>(qb, kb, vTb, vmsum, lengths, O);
}

// Round 14
// 82.116 us; speedup vs baseline: 1.1780x; 1.0052x over previous
//
#include <hip/hip_runtime.h>
#include <hip/hip_bf16.h>

typedef short bf16x8 __attribute__((ext_vector_type(8)));
typedef float f32x4 __attribute__((ext_vector_type(4)));
typedef unsigned int u32;
typedef u32 u32x4 __attribute__((ext_vector_type(4)));

#define T_SEQ 2048
#define NB 8
#define NEGB (-1e30f)

__device__ inline unsigned short f2bf(float f) {
  unsigned u = __builtin_bit_cast(unsigned, f);
  u += 0x7FFFu + ((u >> 16) & 1u);   // round-to-nearest-even
  return (unsigned short)(u >> 16);
}
__device__ inline float bf2f(unsigned short h) {
  unsigned u = ((unsigned)h) << 16;
  return __builtin_bit_cast(float, u);
}
__device__ inline u32 cvt2(float a, float b) {  // v_cvt_pk_bf16_f32 via HIP
  __hip_bfloat162 h = __float22bfloat162_rn(make_float2(a, b));
  u32 r;
  __builtin_memcpy(&r, &h, 4);
  return r;
}
__device__ inline bf16x8 pack8(float4 a, float4 b) {
  u32x4 p;
  p[0] = cvt2(a.x, a.y);
  p[1] = cvt2(a.z, a.w);
  p[2] = cvt2(b.x, b.y);
  p[3] = cvt2(b.z, b.w);
  return __builtin_bit_cast(bf16x8, p);
}
__device__ inline f32x4 mfma16(bf16x8 a, bf16x8 b, f32x4 c) {
  return __builtin_amdgcn_mfma_f32_16x16x32_bf16(a, b, c, 0, 0, 0);
}
// async 16B global -> LDS (DMA). ldsptr wave-uniform; lane l lands at +l*16.
// (aux=2 "NT" variant stays reverted — R12 showed it costs in the timed regime)
__device__ __forceinline__ void gl_lds16(const void* g, void* l) {
  __builtin_amdgcn_global_load_lds(
      (const __attribute__((address_space(1))) void*)g,
      (__attribute__((address_space(3))) void*)l, 16, 0, 0);
}

// ---- prep: fused frag-ordered WT (blocks 0..767) + mask meta (768..775) ----
// wt2[mi][ks(32)][ntg(4)][lane(64)][i(8)] (bf16):
//   element = W_mi[k = ks*32 + (lane>>4)*8 + i][n = ntg*16 + (lane&15)]
// -> a W-frag load is one PERFECT ascending 1KB wave instruction (R8-validated).
__global__ void prep_k(const float* Wq, const float* Wk, const float* Wv,
                       unsigned short* wt, const unsigned char* m,
                       int* lengths, float* vmsum) {
  int tid = threadIdx.x;
  if (blockIdx.x < 768) {
    int e = blockIdx.x * 256 + tid;  // 768*256 == 3*65536 exactly
    int i = e & 7;
    int lane = (e >> 3) & 63;
    int nt = (e >> 9) & 3;
    int ks = (e >> 11) & 31;
    int mi = e >> 16;
    int kk = ks * 32 + (lane >> 4) * 8 + i;
    int n = nt * 16 + (lane & 15);
    const float* W = (mi == 0) ? Wq : (mi == 1) ? Wk : Wv;
    wt[e] = f2bf(W[kk * 64 + n]);
    return;
  }
  int b = blockIdx.x - 768;
  if (tid < 64) vmsum[b * 64 + tid] = 0.f;  // stream-ordered before proj_k
  // int32 0/1 storage has 1-bytes ONLY at byte%4==0; bool padding always has
  // a misaligned 1. ones==0 -> both interpretations agree anyway.
  int lo = 0, lb = 0;
  for (int i = tid; i < NB * T_SEQ; i += 256) {
    int v = (m[i] != 0);
    lo += v;
    if (i & 3) lb += v;
  }
  for (int off = 32; off >= 1; off >>= 1) {
    lo += __shfl_xor(lo, off);
    lb += __shfl_xor(lb, off);
  }
  __shared__ int s0[4], s1[4], ws2[4];
  if ((tid & 63) == 0) { s0[tid >> 6] = lo; s1[tid >> 6] = lb; }
  __syncthreads();
  int ones = s0[0] + s0[1] + s0[2] + s0[3];
  int bad = s1[0] + s1[1] + s1[2] + s1[3];
  int flag = (ones > 0 && bad == 0);  // 1 => int32 storage
  int cnt = 0;
  if (flag) {
    const int* mi2 = (const int*)m;
    for (int t = tid; t < T_SEQ; t += 256) cnt += (mi2[b * T_SEQ + t] == 0);
  } else {
    for (int t = tid; t < T_SEQ; t += 256) cnt += (m[b * T_SEQ + t] == 0);
  }
  for (int off = 32; off >= 1; off >>= 1) cnt += __shfl_xor(cnt, off);
  __syncthreads();
  if ((tid & 63) == 0) ws2[tid >> 6] = cnt;
  __syncthreads();
  if (tid == 0) lengths[b] = ws2[0] + ws2[1] + ws2[2] + ws2[3];
}

// Projection GEMM (R6 structure). Change this round: W frags loaded straight
// from frag-ordered wt2 into registers (L2-hot 1KB ascending loads) instead of
// LDS-staged — removes 1 DMA from the barrier-gated chain (vmcnt 3->2),
// frees 16KB LDS, kills the wss bank conflicts.
__global__ __launch_bounds__(512, 4) void proj_k(
    const float* Q, const float* K, const float* V, const unsigned short* wt,
    unsigned short* qo, unsigned short* ko, unsigned short* vTb, float* vmsum) {
  __shared__ float xs[2][4096];  // 16 KB x2: [row][k] f32 (pre-swizzled)
  int mi = blockIdx.y;
  const float* X = (mi == 0) ? Q : (mi == 1) ? K : V;
  const unsigned short* wtm = wt + mi * 65536;
  int tid = threadIdx.x;
  int w = tid >> 6, lane = tid & 63, l15 = lane & 15, g = lane >> 4;
  int wr = w >> 1, wc = w & 1;
  int r0b = blockIdx.x * 64;

  // staging addresses: per wave exactly 2 gl_lds instrs/chunk
  int segA = w * 2;
  int rowA0 = segA * 4 + (lane >> 4);
  int rowA1 = rowA0 + 4;
  int colA0 = ((lane & 15) ^ (rowA0 & 15)) * 4;
  int colA1 = ((lane & 15) ^ (rowA1 & 15)) * 4;
  const float* srcA0 = X + (size_t)(r0b + rowA0) * 1024 + colA0;
  const float* srcA1 = X + (size_t)(r0b + rowA1) * 1024 + colA1;

  f32x4 acc[2];
  acc[0] = 0; acc[1] = 0;

#define STAGE(buf, kc2)                                          \
  do {                                                           \
    gl_lds16(srcA0 + (kc2) * 64, &xs[buf][segA * 256]);          \
    gl_lds16(srcA1 + (kc2) * 64, &xs[buf][segA * 256 + 256]);    \
  } while (0)

  STAGE(0, 0);  // prologue: chunk 0 in flight

  int arow = wr * 16 + l15;
  // W frag base for this lane/wc: frag(ksg,ntg) at wtm + ksg*2048 + ntg*512 + lane*8
  const unsigned short* wfb = wtm + wc * 1024 + lane * 8;
  for (int kc = 0; kc < 16; ++kc) {
    int cur = kc & 1;
    if (kc < 15) {
      STAGE(cur ^ 1, kc + 1);  // overwrite-safe: post-compute barrier of kc-1
      // wait chunk kc only; chunk kc+1's 2 loads REMAIN IN FLIGHT (T4)
      asm volatile("s_waitcnt vmcnt(2)" ::: "memory");
    } else {
      asm volatile("s_waitcnt vmcnt(0)" ::: "memory");
    }
    __builtin_amdgcn_s_barrier();  // raw: no compiler vmcnt(0) drain
#pragma unroll
    for (int ks = 0; ks < 2; ++ks) {
      int lb0 = ks * 8 + g * 2;
      float4 fa = *(const float4*)&xs[cur][arow * 64 + ((lb0 ^ l15) * 4)];
      float4 fb = *(const float4*)&xs[cur][arow * 64 + (((lb0 + 1) ^ l15) * 4)];
      bf16x8 a = pack8(fa, fb);
      const bf16x8* wb =
          (const bf16x8*)(wfb + (size_t)(kc * 2 + ks) * 2048);
      acc[0] = mfma16(a, wb[0], acc[0]);    // ntg = wc*2
      acc[1] = mfma16(a, wb[64], acc[1]);   // ntg = wc*2+1 (+512 shorts)
    }
    if (kc < 15) {
      // my LDS reads must retire before others' next STAGE overwrites
      asm volatile("s_waitcnt lgkmcnt(0)" ::: "memory");
      __builtin_amdgcn_s_barrier();
    }
  }
#undef STAGE

  // D layout: col = lane&15, row = g*4 + vv
#pragma unroll
  for (int nt = 0; nt < 2; ++nt)
#pragma unroll
    for (int vv = 0; vv < 4; ++vv) {
      int rr = r0b + wr * 16 + g * 4 + vv;
      int c = wc * 32 + nt * 16 + l15;
      float val = acc[nt][vv];
      if (mi == 0) {
        qo[(size_t)rr * 64 + c] = f2bf(val * 0.03125f);  // fold C^-0.5
      } else if (mi == 1) {
        ko[(size_t)rr * 64 + c] = f2bf(val);
      } else {
        int bb = rr >> 11, ts = rr & 2047;
        // tile-blocked vT: [b][t/32][d][t%32]
        vTb[(((size_t)bb * 64 + (ts >> 5)) * 64 + c) * 32 + (ts & 31)] =
            f2bf(val);
      }
    }

  if (mi == 2) {  // fold v column-sums into vmsum[b][d]
    float ps0 = acc[0][0] + acc[0][1] + acc[0][2] + acc[0][3];
    float ps1 = acc[1][0] + acc[1][1] + acc[1][2] + acc[1][3];
    __syncthreads();  // K-loop LDS fully retired; reuse xs as scratch
    float* rb = (float*)xs;  // [64 cols][16 contributors]
    rb[(wc * 32 + l15) * 16 + (wr * 4 + g)] = ps0;
    rb[(wc * 32 + 16 + l15) * 16 + (wr * 4 + g)] = ps1;
    __syncthreads();
    if (tid < 64) {
      float s = 0.f;
#pragma unroll
      for (int i = 0; i < 16; ++i) s += rb[tid * 16 + i];
      atomicAdd(&vmsum[(blockIdx.x >> 5) * 64 + tid], s);
    }
  }
}

// Flash attention: 512 threads = 8 waves = 4 key-chunks x 2 row-groups;
// 32 q-rows per block; 512 blocks (2/CU), complementary work pairing.
// T14 K/V prefetch; merge epilogue now uses ALL 8 waves (4 rows each).
__global__ __launch_bounds__(512, 4) void attn_k(
    const unsigned short* q, const unsigned short* k, const unsigned short* vTb,
    const float* vmsum, const int* lengths, float* Out) {
  __shared__ unsigned short pL[8][16][40];      // per-wave P round-trip
  __shared__ unsigned short oP[4][2][16][64];   // bf16 partial O [j][r][row][col]
  __shared__ float mP[4][2][16], lP[4][2][16];

  // complementary work pairing: co-resident blocks sum to ~constant work
  int id = blockIdx.x;
  int raw = id & 63, b = id >> 6;
  int xx = (raw + 8 * b) & 63;
  int tile = (xx < 32) ? xx : 95 - xx;   // bijective on 0..63
  int t0 = tile * 32;

  int tid = threadIdx.x;
  int w = tid >> 6, lane = tid & 63;
  int j = w >> 1, r = w & 1;
  int l15 = lane & 15, g = lane >> 4;
  int t_base = t0 + r * 16;

  const bf16x8* qrow =
      (const bf16x8*)(q + ((size_t)b * T_SEQ + t_base + l15) * 64);
  bf16x8 aq0 = qrow[g];
  bf16x8 aq1 = qrow[4 + g];

  f32x4 o[4];
  float m[4], l[4];
#pragma unroll
  for (int i = 0; i < 4; ++i) { o[i] = 0; m[i] = NEGB; l[i] = 0.f; }

  const bf16x8* kch = (const bf16x8*)k + (size_t)b * T_SEQ * 8;
  const unsigned short* vch = vTb + (size_t)b * 131072;

  // balanced contiguous tile-chunks over this block's NT key-tiles
  int NT = tile + 1;
  int qn = NT >> 2, rem = NT & 3;
  int start = j * qn + (j < rem ? j : rem);
  int end = start + qn + (j < rem ? 1 : 0);
  int capw = ((t_base + 15) >> 5) + 1;
  if (end > capw) end = capw;

  bf16x8 kb00, kb01, kb10, kb11, bv0, bv1, bv2, bv3;
  if (start < end) {  // prologue loads for first tile
    int s0 = start * 32;
    kb00 = kch[(size_t)(s0 + l15) * 8 + g];
    kb01 = kch[(size_t)(s0 + l15) * 8 + 4 + g];
    kb10 = kch[(size_t)(s0 + 16 + l15) * 8 + g];
    kb11 = kch[(size_t)(s0 + 16 + l15) * 8 + 4 + g];
    bv0 = *(const bf16x8*)&vch[((size_t)(start * 64 + l15)) * 32 + g * 8];
    bv1 = *(const bf16x8*)&vch[((size_t)(start * 64 + 16 + l15)) * 32 + g * 8];
    bv2 = *(const bf16x8*)&vch[((size_t)(start * 64 + 32 + l15)) * 32 + g * 8];
    bv3 = *(const bf16x8*)&vch[((size_t)(start * 64 + 48 + l15)) * 32 + g * 8];
  }

  for (int tt = start; tt < end; ++tt) {
    int s0 = tt * 32;
    f32x4 sa0, sa1;
    sa0 = 0; sa1 = 0;
    sa0 = mfma16(aq0, kb00, sa0);
    sa0 = mfma16(aq1, kb01, sa0);
    sa1 = mfma16(aq0, kb10, sa1);
    sa1 = mfma16(aq1, kb11, sa1);

    // T14: issue next tile's 8 loads now; softmax+PV hides their latency
    bf16x8 nk00, nk01, nk10, nk11, nv0, nv1, nv2, nv3;
    bool more = (tt + 1 < end);
    if (more) {
      int s1 = (tt + 1) * 32;
      nk00 = kch[(size_t)(s1 + l15) * 8 + g];
      nk01 = kch[(size_t)(s1 + l15) * 8 + 4 + g];
      nk10 = kch[(size_t)(s1 + 16 + l15) * 8 + g];
      nk11 = kch[(size_t)(s1 + 16 + l15) * 8 + 4 + g];
      int t1 = (tt + 1) * 64;
      nv0 = *(const bf16x8*)&vch[((size_t)(t1 + l15)) * 32 + g * 8];
      nv1 = *(const bf16x8*)&vch[((size_t)(t1 + 16 + l15)) * 32 + g * 8];
      nv2 = *(const bf16x8*)&vch[((size_t)(t1 + 32 + l15)) * 32 + g * 8];
      nv3 = *(const bf16x8*)&vch[((size_t)(t1 + 48 + l15)) * 32 + g * 8];
    }

#pragma unroll
    for (int vv = 0; vv < 4; ++vv) {
      int t = t_base + g * 4 + vv;
      float v0 = (s0 + l15 <= t) ? sa0[vv] : NEGB;
      float v1 = (s0 + 16 + l15 <= t) ? sa1[vv] : NEGB;
      float rm = fmaxf(v0, v1);
#pragma unroll
      for (int off = 8; off >= 1; off >>= 1)
        rm = fmaxf(rm, __shfl_xor(rm, off));
      float mn = fmaxf(m[vv], rm);
      float corr = __expf(m[vv] - mn);
      float p0 = (v0 == NEGB) ? 0.f : __expf(v0 - mn);  // all-masked tile guard
      float p1 = (v1 == NEGB) ? 0.f : __expf(v1 - mn);
      float rs = p0 + p1;
#pragma unroll
      for (int off = 8; off >= 1; off >>= 1) rs += __shfl_xor(rs, off);
      l[vv] = l[vv] * corr + rs;
      m[vv] = mn;
#pragma unroll
      for (int nt = 0; nt < 4; ++nt) o[nt][vv] *= corr;
      pL[w][g * 4 + vv][l15] = f2bf(p0);
      pL[w][g * 4 + vv][16 + l15] = f2bf(p1);
    }
    bf16x8 ap = *(const bf16x8*)&pL[w][l15][g * 8];
    o[0] = mfma16(ap, bv0, o[0]);
    o[1] = mfma16(ap, bv1, o[1]);
    o[2] = mfma16(ap, bv2, o[2]);
    o[3] = mfma16(ap, bv3, o[3]);
    if (more) {
      kb00 = nk00; kb01 = nk01; kb10 = nk10; kb11 = nk11;
      bv0 = nv0; bv1 = nv1; bv2 = nv2; bv3 = nv3;
    }
  }

  __syncthreads();
#pragma unroll
  for (int nt = 0; nt < 4; ++nt)
#pragma unroll
    for (int vv = 0; vv < 4; ++vv)
      oP[j][r][g * 4 + vv][nt * 16 + l15] = f2bf(o[nt][vv]);
  if (l15 == 0) {
#pragma unroll
    for (int vv = 0; vv < 4; ++vv) {
      mP[j][r][g * 4 + vv] = m[vv];
      lP[j][r][g * 4 + vv] = l[vv];
    }
  }
  __syncthreads();

  {  // merge: ALL 8 waves; wave w handles global rows w*4 .. w*4+3
    int len = lengths[b];
#pragma unroll
    for (int rr2 = 0; rr2 < 4; ++rr2) {
      int gr = w * 4 + rr2;
      int rq = gr >> 4, row = gr & 15;
      float m0 = mP[0][rq][row], m1 = mP[1][rq][row];
      float m2 = mP[2][rq][row], m3 = mP[3][rq][row];
      float ms = fmaxf(fmaxf(m0, m1), fmaxf(m2, m3));
      float e0 = __expf(m0 - ms), e1 = __expf(m1 - ms);
      float e2 = __expf(m2 - ms), e3 = __expf(m3 - ms);
      float ls = lP[0][rq][row] * e0 + lP[1][rq][row] * e1 +
                 lP[2][rq][row] * e2 + lP[3][rq][row] * e3;
      float ov = bf2f(oP[0][rq][row][lane]) * e0 +
                 bf2f(oP[1][rq][row][lane]) * e1 +
                 bf2f(oP[2][rq][row][lane]) * e2 +
                 bf2f(oP[3][rq][row][lane]) * e3;
      float val = ov / ls;
      int t = t0 + gr;
      if (t >= len) val = vmsum[b * 64 + lane] * (1.0f / T_SEQ);  // pad row
      Out[((size_t)b * T_SEQ + t) * 64 + lane] = val;
    }
  }
}

extern "C" void kernel_launch(void* const* d_in, const int* in_sizes, int n_in,
                              void* d_out, int out_size, void* d_ws,
                              size_t ws_size, hipStream_t stream) {
  const float* V = (const float*)d_in[0];
  const float* K = (const float*)d_in[1];
  const float* Q = (const float*)d_in[2];
  const float* Wq = (const float*)d_in[3];
  const float* Wk = (const float*)d_in[4];
  const float* Wv = (const float*)d_in[5];
  const unsigned char* mask = (const unsigned char*)d_in[6];
  float* O = (float*)d_out;
  char* ws = (char*)d_ws;

  unsigned short* wt = (unsigned short*)(ws);                        // 384 KiB
  unsigned short* qb = (unsigned short*)(ws + 393216);               // 2 MiB
  unsigned short* kb = (unsigned short*)(ws + 393216 + 2097152);     // 2 MiB
  unsigned short* vTb = (unsigned short*)(ws + 393216 + 2 * 2097152);// 2 MiB
  float* vmsum = (float*)(ws + 393216 + 3 * 2097152);                // 2 KiB
  int* lengths = (int*)(ws + 393216 + 3 * 2097152 + 2048);

  prep_k<<<776, 256, 0, stream>>>(Wq, Wk, Wv, wt, mask, lengths, vmsum);
  proj_k<<<dim3(256, 3), 512, 0, stream>>>(Q, K, V, wt, qb, kb, vTb, vmsum);
  attn_k<<<512, 512, 0, stream>>>(qb, kb, vTb, vmsum, lengths, O);
}